// Round 1
// baseline (1711.332 us; speedup 1.0000x reference)
//
#include <hip/hip_runtime.h>
#include <math.h>

#define TT 1024

// ws layout (floats)
#define OFF_Q      0u
#define OFF_K      4194304u
#define OFF_V      8388608u
#define OFF_ATT    12582912u
#define OFF_COLM   16777216u
#define OFF_COLD   16793600u
#define OFF_ROWS   16809984u
#define OFF_WX     16826368u
#define OFF_W1T    16842752u
#define OFF_W2T    17039360u
#define OFF_S      17235968u
// h1 reuses the Q region (q dead after sgemm chunk loop)

__device__ __forceinline__ float blk_reduce_sum(float v, float* red) {
    int tid = threadIdx.x;
    red[tid] = v; __syncthreads();
    for (int off = 128; off > 0; off >>= 1) {
        if (tid < off) red[tid] += red[tid + off];
        __syncthreads();
    }
    float r = red[0]; __syncthreads();
    return r;
}

// ---- weight norm: w = g * v / ||v||_(in,k), written transposed [k][ci][o] ----
__global__ void wnorm_kernel(const float* __restrict__ v, const float* __restrict__ g,
                             float* __restrict__ wT) {
    __shared__ float red[256];
    int o = blockIdx.x, tid = threadIdx.x;
    float vals[3];
    float s = 0.f;
#pragma unroll
    for (int r = 0; r < 3; ++r) {
        vals[r] = v[o * 768 + r * 256 + tid];
        s += vals[r] * vals[r];
    }
    float tot = blk_reduce_sum(s, red);
    float scale = g[o] / sqrtf(tot);
#pragma unroll
    for (int r = 0; r < 3; ++r) {
        int idx = r * 256 + tid;
        int i = idx / 3, kk = idx - i * 3;
        wT[(((kk << 8) + i) << 8) + o] = vals[r] * scale;
    }
}

// ---- QKV projection: out[b][t][k] = sum_c x[b][c][t] * W[c][k] + bias ----
// grid (16 t-tiles, 12 = which*4+ktile, 16 b), block 256
__global__ void qkv_kernel(const float* __restrict__ x,
                           const float* __restrict__ Wq, const float* __restrict__ bq,
                           const float* __restrict__ Wk, const float* __restrict__ bk,
                           const float* __restrict__ Wv, const float* __restrict__ bv,
                           float* __restrict__ qo, float* __restrict__ ko, float* __restrict__ vo) {
    int tt = blockIdx.x, wy = blockIdx.y, b = blockIdx.z;
    int which = wy >> 2, kt = wy & 3;
    const float* W    = (which == 0) ? Wq : (which == 1) ? Wk : Wv;
    const float* bias = (which == 0) ? bq : (which == 1) ? bk : bv;
    float* out        = (which == 0) ? qo : (which == 1) ? ko : vo;
    int kg = threadIdx.x >> 4, tg = threadIdx.x & 15;
    int t0 = (tt << 6) + (tg << 2), k0 = (kt << 6) + (kg << 2);
    const float* xb = x + ((size_t)b << 18);
    float acc[4][4] = {};
    for (int c = 0; c < 256; ++c) {
        float4 xv = *(const float4*)&xb[((size_t)c << 10) + t0];
        float4 wv = *(const float4*)&W[(c << 8) + k0];
        float xa[4] = {xv.x, xv.y, xv.z, xv.w};
        float wa[4] = {wv.x, wv.y, wv.z, wv.w};
#pragma unroll
        for (int ti = 0; ti < 4; ++ti)
#pragma unroll
            for (int ki = 0; ki < 4; ++ki)
                acc[ti][ki] += xa[ti] * wa[ki];
    }
    float4 b4 = *(const float4*)&bias[k0];
#pragma unroll
    for (int ti = 0; ti < 4; ++ti) {
        float4 o = make_float4(acc[ti][0] + b4.x, acc[ti][1] + b4.y,
                               acc[ti][2] + b4.z, acc[ti][3] + b4.w);
        *(float4*)&out[(((size_t)b << 10) + t0 + ti) * 256 + k0] = o;
    }
}

// ---- S[b][j][i] = q_j . k_i / 16  (i<=j), else -inf. grid (16 it, 16 jt, nb) ----
__global__ void sgemm_kernel(const float* __restrict__ q, const float* __restrict__ k,
                             float* __restrict__ S, int b0) {
    int it = blockIdx.x, jt = blockIdx.y;
    if (it > jt) return;
    int bl = blockIdx.z, b = b0 + bl;
    int jg = threadIdx.x >> 4, ig = threadIdx.x & 15;
    int j0 = (jt << 6) + (jg << 2), i0 = (it << 6) + (ig << 2);
    const float* qb = q + ((size_t)b << 18);
    const float* kb = k + ((size_t)b << 18);
    float acc[4][4] = {};
    for (int c = 0; c < 256; c += 4) {
        float4 av[4], bv[4];
#pragma unroll
        for (int jj = 0; jj < 4; ++jj) av[jj] = *(const float4*)&qb[((j0 + jj) << 8) + c];
#pragma unroll
        for (int ii = 0; ii < 4; ++ii) bv[ii] = *(const float4*)&kb[((i0 + ii) << 8) + c];
#pragma unroll
        for (int jj = 0; jj < 4; ++jj)
#pragma unroll
            for (int ii = 0; ii < 4; ++ii)
                acc[jj][ii] += av[jj].x * bv[ii].x + av[jj].y * bv[ii].y +
                               av[jj].z * bv[ii].z + av[jj].w * bv[ii].w;
    }
    float* Sb = S + ((size_t)bl << 20);
#pragma unroll
    for (int jj = 0; jj < 4; ++jj) {
        int j = j0 + jj;
        float4 o;
        o.x = (i0 + 0 <= j) ? acc[jj][0] * 0.0625f : -INFINITY;
        o.y = (i0 + 1 <= j) ? acc[jj][1] * 0.0625f : -INFINITY;
        o.z = (i0 + 2 <= j) ? acc[jj][2] * 0.0625f : -INFINITY;
        o.w = (i0 + 3 <= j) ? acc[jj][3] * 0.0625f : -INFINITY;
        *(float4*)&Sb[((size_t)j << 10) + i0] = o;
    }
}

// ---- per-column (softmax over query axis j) online max/sum-exp. grid (16 it, nb) ----
__global__ void colstats_kernel(const float* __restrict__ S, float* __restrict__ colM,
                                float* __restrict__ colD, int b0) {
    int it = blockIdx.x, bl = blockIdx.y, b = b0 + bl;
    int tid = threadIdx.x;
    int lane = tid & 63, g = tid >> 6;
    int i = (it << 6) + lane;
    const float* Sb = S + ((size_t)bl << 20);
    float m = -INFINITY, d = 0.f;
    for (int j = (it << 6) + g; j < TT; j += 4) {
        float s = Sb[((size_t)j << 10) + i];
        if (s > -1e37f) {
            float m2 = fmaxf(m, s);
            d = d * expf(m - m2) + expf(s - m2);
            m = m2;
        }
    }
    __shared__ float sm[256], sd[256];
    sm[tid] = m; sd[tid] = d;
    __syncthreads();
    if (tid < 64) {
        float m0 = sm[tid], m1 = sm[64 + tid], m2 = sm[128 + tid], m3 = sm[192 + tid];
        float M = fmaxf(fmaxf(m0, m1), fmaxf(m2, m3));
        float D = sd[tid] * expf(m0 - M) + sd[64 + tid] * expf(m1 - M) +
                  sd[128 + tid] * expf(m2 - M) + sd[192 + tid] * expf(m3 - M);
        colM[(b << 10) + (it << 6) + tid] = M;
        colD[(b << 10) + (it << 6) + tid] = D;
    }
}

// ---- P = exp(S - colM)/colD in place, plus row sums. grid (1024 j, nb) ----
__global__ void pexp_kernel(float* __restrict__ S, const float* __restrict__ colM,
                            const float* __restrict__ colD, float* __restrict__ rowsum, int b0) {
    int j = blockIdx.x, bl = blockIdx.y, b = b0 + bl;
    int tid = threadIdx.x;
    float* row = S + ((size_t)bl << 20) + ((size_t)j << 10);
    float4 s4 = ((const float4*)row)[tid];
    float4 m4 = ((const float4*)(colM + (b << 10)))[tid];
    float4 d4 = ((const float4*)(colD + (b << 10)))[tid];
    int i0 = tid << 2;
    float4 p;
    p.x = (i0 + 0 <= j) ? expf(s4.x - m4.x) / d4.x : 0.f;
    p.y = (i0 + 1 <= j) ? expf(s4.y - m4.y) / d4.y : 0.f;
    p.z = (i0 + 2 <= j) ? expf(s4.z - m4.z) / d4.z : 0.f;
    p.w = (i0 + 3 <= j) ? expf(s4.w - m4.w) / d4.w : 0.f;
    ((float4*)row)[tid] = p;
    __shared__ float red[256];
    float tot = blk_reduce_sum(p.x + p.y + p.z + p.w, red);
    if (tid == 0) rowsum[(b << 10) + j] = tot;
}

// ---- att[b][c][j] = sum_i P[j][i] * v[i][c]. grid (16 jt, 4 ct, nb) ----
__global__ void pv_kernel(const float* __restrict__ P, const float* __restrict__ v,
                          float* __restrict__ att, int b0) {
    int jt = blockIdx.x, ct = blockIdx.y, bl = blockIdx.z, b = b0 + bl;
    int jg = threadIdx.x >> 4, cg = threadIdx.x & 15;
    int j0 = (jt << 6) + (jg << 2), c0 = (ct << 6) + (cg << 2);
    const float* Pb = P + ((size_t)bl << 20);
    const float* vb = v + ((size_t)b << 18);
    float acc[4][4] = {};
    int imax = (jt << 6) + 64;   // P is exactly 0 for i>j, so no masking needed
    for (int i = 0; i < imax; i += 4) {
        float pa[4][4];
#pragma unroll
        for (int jj = 0; jj < 4; ++jj) {
            float4 pr = *(const float4*)&Pb[((size_t)(j0 + jj) << 10) + i];
            pa[jj][0] = pr.x; pa[jj][1] = pr.y; pa[jj][2] = pr.z; pa[jj][3] = pr.w;
        }
        float va[4][4];
#pragma unroll
        for (int r = 0; r < 4; ++r) {
            float4 vv = *(const float4*)&vb[((i + r) << 8) + c0];
            va[r][0] = vv.x; va[r][1] = vv.y; va[r][2] = vv.z; va[r][3] = vv.w;
        }
#pragma unroll
        for (int jj = 0; jj < 4; ++jj)
#pragma unroll
            for (int r = 0; r < 4; ++r)
#pragma unroll
                for (int cc = 0; cc < 4; ++cc)
                    acc[jj][cc] += pa[jj][r] * va[r][cc];
    }
#pragma unroll
    for (int cc = 0; cc < 4; ++cc) {
        float4 o = make_float4(acc[0][cc], acc[1][cc], acc[2][cc], acc[3][cc]);
        *(float4*)&att[(((size_t)(b << 8) + c0 + cc) << 10) + j0] = o;
    }
}

// ---- weight_x[b][t] = softmax_t(rowsum[b][t]). grid (16) ----
__global__ void wx_kernel(const float* __restrict__ rowsum, float* __restrict__ wx) {
    int b = blockIdx.x, tid = threadIdx.x;
    __shared__ float red[256];
    float4 r4 = ((const float4*)(rowsum + ((size_t)b << 10)))[tid];
    float mx = fmaxf(fmaxf(r4.x, r4.y), fmaxf(r4.z, r4.w));
    red[tid] = mx; __syncthreads();
    for (int off = 128; off > 0; off >>= 1) {
        if (tid < off) red[tid] = fmaxf(red[tid], red[tid + off]);
        __syncthreads();
    }
    float M = red[0]; __syncthreads();
    float e0 = expf(r4.x - M), e1 = expf(r4.y - M), e2 = expf(r4.z - M), e3 = expf(r4.w - M);
    float Z = blk_reduce_sum(e0 + e1 + e2 + e3, red);
    float4 o = make_float4(e0 / Z, e1 / Z, e2 / Z, e3 / Z);
    ((float4*)(wx + ((size_t)b << 10)))[tid] = o;
}

// ---- causal conv (k=3, left pad 2) + relu; optional fused residual epilogue ----
// grid (16 tt, 4 ot, 16 b)
__global__ void conv_kernel(const float* __restrict__ in, const float* __restrict__ wT,
                            const float* __restrict__ bias, float* __restrict__ out,
                            const float* __restrict__ x, const float* __restrict__ wx,
                            int fuse) {
    int tt = blockIdx.x, ot = blockIdx.y, b = blockIdx.z;
    int og = threadIdx.x >> 4, tg = threadIdx.x & 15;
    int t0 = (tt << 6) + (tg << 2), o0 = (ot << 6) + (og << 2);
    const float* inb = in + ((size_t)b << 18);
    float acc[4][4] = {};   // [oo][tl]
    for (int ci = 0; ci < 256; ++ci) {
        const float* r = inb + ((size_t)ci << 10);
        float4 a = *(const float4*)&r[t0];
        float sm1 = (t0 >= 1) ? r[t0 - 1] : 0.f;
        float sm2 = (t0 >= 2) ? r[t0 - 2] : 0.f;
        float win[6] = {sm2, sm1, a.x, a.y, a.z, a.w};
        float wa[3][4];
#pragma unroll
        for (int kk = 0; kk < 3; ++kk) {
            float4 w4 = *(const float4*)&wT[(((kk << 8) + ci) << 8) + o0];
            wa[kk][0] = w4.x; wa[kk][1] = w4.y; wa[kk][2] = w4.z; wa[kk][3] = w4.w;
        }
#pragma unroll
        for (int kk = 0; kk < 3; ++kk)
#pragma unroll
            for (int oo = 0; oo < 4; ++oo)
#pragma unroll
                for (int tl = 0; tl < 4; ++tl)
                    acc[oo][tl] += wa[kk][oo] * win[kk + tl];
    }
#pragma unroll
    for (int oo = 0; oo < 4; ++oo) {
        int o = o0 + oo;
        float bo = bias[o];
        float4 h;
        h.x = fmaxf(acc[oo][0] + bo, 0.f);
        h.y = fmaxf(acc[oo][1] + bo, 0.f);
        h.z = fmaxf(acc[oo][2] + bo, 0.f);
        h.w = fmaxf(acc[oo][3] + bo, 0.f);
        size_t orow = (((size_t)(b << 8) + o) << 10);
        if (fuse) {
            float4 xv = *(const float4*)&x[orow + t0];
            float4 wv = *(const float4*)&wx[(b << 10) + t0];
            h.x = fmaxf(h.x + xv.x * (1.f + wv.x), 0.f);
            h.y = fmaxf(h.y + xv.y * (1.f + wv.y), 0.f);
            h.z = fmaxf(h.z + xv.z * (1.f + wv.z), 0.f);
            h.w = fmaxf(h.w + xv.w * (1.f + wv.w), 0.f);
        }
        *(float4*)&out[orow + t0] = h;
    }
}

extern "C" void kernel_launch(void* const* d_in, const int* in_sizes, int n_in,
                              void* d_out, int out_size, void* d_ws, size_t ws_size,
                              hipStream_t stream) {
    const float* x   = (const float*)d_in[0];
    const float* Wq  = (const float*)d_in[1];
    const float* bq  = (const float*)d_in[2];
    const float* Wk  = (const float*)d_in[3];
    const float* bk  = (const float*)d_in[4];
    const float* Wv  = (const float*)d_in[5];
    const float* bv  = (const float*)d_in[6];
    const float* c1v = (const float*)d_in[7];
    const float* c1g = (const float*)d_in[8];
    const float* c1b = (const float*)d_in[9];
    const float* c2v = (const float*)d_in[10];
    const float* c2g = (const float*)d_in[11];
    const float* c2b = (const float*)d_in[12];
    float* out = (float*)d_out;
    float* ws = (float*)d_ws;

    float* q    = ws + OFF_Q;
    float* k    = ws + OFF_K;
    float* v    = ws + OFF_V;
    float* att  = ws + OFF_ATT;
    float* h1   = q;  // reuse: q dead after attention
    float* colM = ws + OFF_COLM;
    float* colD = ws + OFF_COLD;
    float* rows = ws + OFF_ROWS;
    float* wxp  = ws + OFF_WX;
    float* w1T  = ws + OFF_W1T;
    float* w2T  = ws + OFF_W2T;
    float* S    = ws + OFF_S;

    dim3 blk(256);

    wnorm_kernel<<<dim3(256), blk, 0, stream>>>(c1v, c1g, w1T);
    wnorm_kernel<<<dim3(256), blk, 0, stream>>>(c2v, c2g, w2T);
    qkv_kernel<<<dim3(16, 12, 16), blk, 0, stream>>>(x, Wq, bq, Wk, bk, Wv, bv, q, k, v);

    // batch-chunk the score matrix if ws is small (deterministic in ws_size -> graph safe)
    size_t ws_floats = ws_size / sizeof(float);
    size_t avail = (ws_floats > OFF_S) ? (ws_floats - OFF_S) : 0;
    int bmax = (int)(avail / (1024u * 1024u));
    if (bmax < 1) bmax = 1;
    if (bmax > 16) bmax = 16;
    for (int b0 = 0; b0 < 16; b0 += bmax) {
        int nb = (16 - b0 < bmax) ? (16 - b0) : bmax;
        sgemm_kernel<<<dim3(16, 16, nb), blk, 0, stream>>>(q, k, S, b0);
        colstats_kernel<<<dim3(16, nb), blk, 0, stream>>>(S, colM, colD, b0);
        pexp_kernel<<<dim3(1024, nb), blk, 0, stream>>>(S, colM, colD, rows, b0);
        pv_kernel<<<dim3(16, 4, nb), blk, 0, stream>>>(S, v, att, b0);
    }
    wx_kernel<<<dim3(16), blk, 0, stream>>>(rows, wxp);
    conv_kernel<<<dim3(16, 4, 16), blk, 0, stream>>>(att, w1T, c1b, h1,
                                                     (const float*)nullptr,
                                                     (const float*)nullptr, 0);
    conv_kernel<<<dim3(16, 4, 16), blk, 0, stream>>>(h1, w2T, c2b, out, x, wxp, 1);
}

// Round 3
// 371.969 us; speedup vs baseline: 4.6007x; 4.6007x over previous
//
#include <hip/hip_runtime.h>
#include <math.h>

typedef __attribute__((ext_vector_type(8))) short s16x8;
typedef __attribute__((ext_vector_type(4))) float f32x4;

__device__ __forceinline__ float b2f(unsigned short u) {
    unsigned int x = ((unsigned int)u) << 16;
    float f; __builtin_memcpy(&f, &x, 4); return f;
}
__device__ __forceinline__ unsigned short f2b(float f) {
    unsigned int x; __builtin_memcpy(&x, &f, 4);
    unsigned int r = x + 0x7FFFu + ((x >> 16) & 1u);
    return (unsigned short)(r >> 16);
}

__device__ __forceinline__ float blk_reduce_sum(float v, float* red) {
    int tid = threadIdx.x;
    red[tid] = v; __syncthreads();
    for (int off = 128; off > 0; off >>= 1) {
        if (tid < off) red[tid] += red[tid + off];
        __syncthreads();
    }
    float r = red[0]; __syncthreads();
    return r;
}

// ---------- prep: x [b][c][t] fp32 -> xT [b][t][c] bf16 ----------
__global__ __launch_bounds__(256) void txp_x(const float* __restrict__ x,
                                             unsigned short* __restrict__ xT) {
    __shared__ float t[32][33];
    int tt = blockIdx.x, ct = blockIdx.y, b = blockIdx.z;
    int col = threadIdx.x & 31, rq = threadIdx.x >> 5;
    const float* xb = x + (((size_t)b * 256 + ct * 32) << 10) + (tt << 5);
#pragma unroll
    for (int p = 0; p < 4; ++p) { int r = rq + p * 8; t[r][col] = xb[((size_t)r << 10) + col]; }
    __syncthreads();
    unsigned short* o = xT + ((size_t)b << 18) + ((size_t)(tt << 5) << 8) + (ct << 5);
#pragma unroll
    for (int p = 0; p < 4; ++p) { int tr = rq + p * 8; o[((size_t)tr << 8) + col] = f2b(t[col][tr]); }
}

// ---------- prep: Wq/Wk/Wv [c][k] fp32 -> WT [k][c] bf16 (3 matrices) ----------
__global__ __launch_bounds__(256) void txp_w(const float* __restrict__ Wq, const float* __restrict__ Wk,
                                             const float* __restrict__ Wv, unsigned short* __restrict__ WT) {
    __shared__ float t[32][33];
    int kt = blockIdx.x, ct = blockIdx.y, z = blockIdx.z;
    const float* W = (z == 0) ? Wq : (z == 1) ? Wk : Wv;
    int col = threadIdx.x & 31, rq = threadIdx.x >> 5;
    const float* wb = W + ((ct * 32) << 8) + (kt << 5);
#pragma unroll
    for (int p = 0; p < 4; ++p) { int r = rq + p * 8; t[r][col] = wb[(r << 8) + col]; }
    __syncthreads();
    unsigned short* o = WT + (z << 16) + ((kt << 5) << 8) + (ct << 5);
#pragma unroll
    for (int p = 0; p < 4; ++p) { int tr = rq + p * 8; o[(tr << 8) + col] = f2b(t[col][tr]); }
}

// ---------- prep: weight-norm conv weights -> wK [kk][o][ci] bf16 ----------
__global__ __launch_bounds__(256) void wnorm_k(const float* __restrict__ v, const float* __restrict__ g,
                                               unsigned short* __restrict__ wK) {
    __shared__ float red[256];
    int o = blockIdx.x, tid = threadIdx.x;
    float a0 = v[o * 768 + tid * 3 + 0];
    float a1 = v[o * 768 + tid * 3 + 1];
    float a2 = v[o * 768 + tid * 3 + 2];
    float tot = blk_reduce_sum(a0 * a0 + a1 * a1 + a2 * a2, red);
    float sc = g[o] / sqrtf(tot);
    wK[0 * 65536 + o * 256 + tid] = f2b(a0 * sc);
    wK[1 * 65536 + o * 256 + tid] = f2b(a1 * sc);
    wK[2 * 65536 + o * 256 + tid] = f2b(a2 * sc);
}

// ---------- zero the 2 leading pad rows of attT / h1T per batch ----------
__global__ void zero_pads_k(unsigned short* attT, unsigned short* h1T) {
    int idx = blockIdx.x * 256 + threadIdx.x;   // 32 blocks -> 8192 = 16b * 512
    int b = idx >> 9, r = idx & 511;
    attT[(size_t)b * 262656 + r] = 0;
    h1T[(size_t)b * 262656 + r] = 0;
}

// ---------- generic bf16 MFMA GEMM: C = A . B^T  (A [M][K], B [N][K], K-contiguous) ----------
// 128x128 tile, 256 thr = 4 waves (2x2), each wave 64x64 = 4x4 frags of 16x16x32.
// MODE 0: q/k proj   out bf16 [t][256]+bias[col]
// MODE 1: v proj     out vT bf16 [c][1024]+bias[row]
// MODE 2: scores     out S bf16 [j][1024]*1/16, skip tiles nt>mt
// MODE 3: PV         A=P (chunk batch), B=vT, K=(mt+1)*128, out attT padded rows
// MODE 4: conv1      A=attT shifted 3 segs, B=w1K, +bias relu, out h1T padded
// MODE 5: conv2      A=h1T shifted, B=w2K, +bias relu, + x*(1+wx), relu, out fp32 [o][t]
template<int MODE>
__global__ __launch_bounds__(256) void gemm_k(const unsigned short* __restrict__ Ab,
                                              const unsigned short* __restrict__ Bb,
                                              unsigned short* __restrict__ o16,
                                              float* __restrict__ o32,
                                              const float* __restrict__ bias,
                                              const float* __restrict__ xres,
                                              const float* __restrict__ wxv, int b0) {
    int nt = blockIdx.x, mt = blockIdx.y, bz = blockIdx.z;
    if constexpr (MODE == 2) { if (nt > mt) return; }
    int b = b0 + bz;
    int m0 = mt << 7, n0 = nt << 7;
    constexpr int LDA = (MODE == 3) ? 1024 : 256;
    constexpr int LDB = (MODE == 3) ? 1024 : 256;
    const unsigned short* A;
    const unsigned short* B;
    if constexpr (MODE == 0)      { A = Ab + ((size_t)b << 18); B = Bb; }
    else if constexpr (MODE == 1) { A = Ab;                      B = Bb + ((size_t)b << 18); }
    else if constexpr (MODE == 2) { A = Ab + ((size_t)b << 18); B = Bb + ((size_t)b << 18); }
    else if constexpr (MODE == 3) { A = Ab + ((size_t)bz << 20); B = Bb + ((size_t)b << 18); }
    else                          { A = Ab + (size_t)b * 262656; B = Bb; }

    int tid = threadIdx.x;
    int wid = tid >> 6, lane = tid & 63;
    int wr = wid >> 1, wc = wid & 1;
    int lrow = lane & 15, koct = lane >> 4;
    int sr = tid >> 2, sk = (tid & 3) << 3;

    __shared__ short As[128 * 40];
    __shared__ short Bs[128 * 40];

    f32x4 acc[4][4];
#pragma unroll
    for (int m = 0; m < 4; ++m)
#pragma unroll
        for (int n = 0; n < 4; ++n) acc[m][n] = (f32x4){0.f, 0.f, 0.f, 0.f};

    constexpr int NSEG = (MODE >= 4) ? 3 : 1;
    int ksteps = (MODE == 3) ? ((mt + 1) << 2) : 8;

    for (int seg = 0; seg < NSEG; ++seg) {
        const unsigned short* Ar;
        const unsigned short* Br;
        if constexpr (MODE >= 4) {
            Ar = A + (size_t)(m0 + seg) * 256;            // shifted padded rows
            Br = B + (seg << 16) + (size_t)n0 * 256;      // weight plane kk=seg
        } else {
            Ar = A + (size_t)m0 * LDA;
            Br = B + (size_t)n0 * LDB;
        }
        for (int ks = 0; ks < ksteps; ++ks) {
            int k0 = ks << 5;
            __syncthreads();
            *(s16x8*)&As[sr * 40 + sk]        = *(const s16x8*)&Ar[(size_t)sr * LDA + k0 + sk];
            *(s16x8*)&As[(sr + 64) * 40 + sk] = *(const s16x8*)&Ar[(size_t)(sr + 64) * LDA + k0 + sk];
            *(s16x8*)&Bs[sr * 40 + sk]        = *(const s16x8*)&Br[(size_t)sr * LDB + k0 + sk];
            *(s16x8*)&Bs[(sr + 64) * 40 + sk] = *(const s16x8*)&Br[(size_t)(sr + 64) * LDB + k0 + sk];
            __syncthreads();
            s16x8 af[4], bf[4];
#pragma unroll
            for (int m = 0; m < 4; ++m)
                af[m] = *(const s16x8*)&As[(wr * 64 + m * 16 + lrow) * 40 + (koct << 3)];
#pragma unroll
            for (int n = 0; n < 4; ++n)
                bf[n] = *(const s16x8*)&Bs[(wc * 64 + n * 16 + lrow) * 40 + (koct << 3)];
#pragma unroll
            for (int m = 0; m < 4; ++m)
#pragma unroll
                for (int n = 0; n < 4; ++n)
                    acc[m][n] = __builtin_amdgcn_mfma_f32_16x16x32_bf16(af[m], bf[n], acc[m][n], 0, 0, 0);
        }
    }

    int rb = m0 + wr * 64 + koct * 4;
    int cb = n0 + wc * 64 + lrow;
#pragma unroll
    for (int m = 0; m < 4; ++m) {
#pragma unroll
        for (int n = 0; n < 4; ++n) {
            int col = cb + n * 16;
#pragma unroll
            for (int j = 0; j < 4; ++j) {
                int row = rb + m * 16 + j;
                float v = acc[m][n][j];
                if constexpr (MODE == 0) {
                    o16[((size_t)b << 18) + ((size_t)row << 8) + col] = f2b(v + bias[col]);
                } else if constexpr (MODE == 1) {
                    o16[((size_t)b << 18) + ((size_t)row << 10) + col] = f2b(v + bias[row]);
                } else if constexpr (MODE == 2) {
                    o16[((size_t)bz << 20) + ((size_t)row << 10) + col] = f2b(v * 0.0625f);
                } else if constexpr (MODE == 3) {
                    o16[(size_t)b * 262656 + ((size_t)(row + 2) << 8) + col] = f2b(v);
                } else if constexpr (MODE == 4) {
                    o16[(size_t)b * 262656 + ((size_t)(row + 2) << 8) + col] =
                        f2b(fmaxf(v + bias[col], 0.f));
                } else {
                    size_t oi = (((size_t)(b << 8) + col) << 10) + row;
                    float h = fmaxf(v + bias[col], 0.f);
                    h = fmaxf(h + xres[oi] * (1.f + wxv[(b << 10) + row]), 0.f);
                    o32[oi] = h;
                }
            }
        }
    }
}

// ---------- per-column softmax stats (softmax over query axis j) ----------
__global__ __launch_bounds__(256) void colstats_k(const unsigned short* __restrict__ S,
                                                  float* __restrict__ colM, float* __restrict__ colD,
                                                  int b0) {
    int it = blockIdx.x, bz = blockIdx.y, b = b0 + bz;
    int tid = threadIdx.x, lane = tid & 63, g = tid >> 6;
    int i = (it << 6) + lane;
    const unsigned short* Sb = S + ((size_t)bz << 20);
    float m = -3.0e38f;
    for (int j = (it << 6) + g; j < 1024; j += 4)
        if (j >= i) m = fmaxf(m, b2f(Sb[((size_t)j << 10) + i]));
    __shared__ float sm[256];
    __shared__ float Msh[64];
    sm[tid] = m; __syncthreads();
    if (tid < 64)
        Msh[tid] = fmaxf(fmaxf(sm[tid], sm[64 + tid]), fmaxf(sm[128 + tid], sm[192 + tid]));
    __syncthreads();
    float M = Msh[lane];
    float d = 0.f;
    for (int j = (it << 6) + g; j < 1024; j += 4)
        if (j >= i) d += expf(b2f(Sb[((size_t)j << 10) + i]) - M);
    __syncthreads();
    sm[tid] = d; __syncthreads();
    if (tid < 64) {
        colM[(b << 10) + (it << 6) + tid] = Msh[tid];
        colD[(b << 10) + (it << 6) + tid] = sm[tid] + sm[64 + tid] + sm[128 + tid] + sm[192 + tid];
    }
}

// ---------- P = exp(S - colM)/colD (bf16 in place) + row sums ----------
__global__ __launch_bounds__(256) void pexp_k(unsigned short* __restrict__ S,
                                              const float* __restrict__ colM,
                                              const float* __restrict__ colD,
                                              float* __restrict__ rowsum, int b0) {
    int j = blockIdx.x, bz = blockIdx.y, b = b0 + bz;
    int tid = threadIdx.x;
    unsigned short* row = S + ((size_t)bz << 20) + ((size_t)j << 10);
    ushort4 s4 = *(const ushort4*)&row[tid << 2];
    float4 m4 = ((const float4*)(colM + (b << 10)))[tid];
    float4 d4 = ((const float4*)(colD + (b << 10)))[tid];
    int i0 = tid << 2;
    float p0 = (i0 + 0 <= j) ? expf(b2f(s4.x) - m4.x) / d4.x : 0.f;
    float p1 = (i0 + 1 <= j) ? expf(b2f(s4.y) - m4.y) / d4.y : 0.f;
    float p2 = (i0 + 2 <= j) ? expf(b2f(s4.z) - m4.z) / d4.z : 0.f;
    float p3 = (i0 + 3 <= j) ? expf(b2f(s4.w) - m4.w) / d4.w : 0.f;
    ushort4 o;
    o.x = f2b(p0); o.y = f2b(p1); o.z = f2b(p2); o.w = f2b(p3);
    *(ushort4*)&row[tid << 2] = o;
    __shared__ float red[256];
    float tot = blk_reduce_sum(p0 + p1 + p2 + p3, red);
    if (tid == 0) rowsum[(b << 10) + j] = tot;
}

// ---------- weight_x[b][t] = softmax_t(rowsum) ----------
__global__ __launch_bounds__(256) void wx_k(const float* __restrict__ rowsum, float* __restrict__ wx) {
    int b = blockIdx.x, tid = threadIdx.x;
    __shared__ float red[256];
    float4 r4 = ((const float4*)(rowsum + ((size_t)b << 10)))[tid];
    float mx = fmaxf(fmaxf(r4.x, r4.y), fmaxf(r4.z, r4.w));
    red[tid] = mx; __syncthreads();
    for (int off = 128; off > 0; off >>= 1) {
        if (tid < off) red[tid] = fmaxf(red[tid], red[tid + off]);
        __syncthreads();
    }
    float M = red[0]; __syncthreads();
    float e0 = expf(r4.x - M), e1 = expf(r4.y - M), e2 = expf(r4.z - M), e3 = expf(r4.w - M);
    float Z = blk_reduce_sum(e0 + e1 + e2 + e3, red);
    float4 o = make_float4(e0 / Z, e1 / Z, e2 / Z, e3 / Z);
    ((float4*)(wx + ((size_t)b << 10)))[tid] = o;
}

extern "C" void kernel_launch(void* const* d_in, const int* in_sizes, int n_in,
                              void* d_out, int out_size, void* d_ws, size_t ws_size,
                              hipStream_t stream) {
    const float* x   = (const float*)d_in[0];
    const float* Wq  = (const float*)d_in[1];
    const float* bq  = (const float*)d_in[2];
    const float* Wk  = (const float*)d_in[3];
    const float* bk  = (const float*)d_in[4];
    const float* Wv  = (const float*)d_in[5];
    const float* bv  = (const float*)d_in[6];
    const float* c1v = (const float*)d_in[7];
    const float* c1g = (const float*)d_in[8];
    const float* c1b = (const float*)d_in[9];
    const float* c2v = (const float*)d_in[10];
    const float* c2g = (const float*)d_in[11];
    const float* c2b = (const float*)d_in[12];
    float* out = (float*)d_out;

    // ws layout in BYTES (all regions disjoint; w1K/w2K are 3*65536*2 = 393216 B each)
    char* w = (char*)d_ws;
    unsigned short* xT   = (unsigned short*)(w + 0);          // 8,388,608
    unsigned short* qb   = (unsigned short*)(w + 8388608);    // 8,388,608
    unsigned short* kb   = (unsigned short*)(w + 16777216);   // 8,388,608
    unsigned short* vT   = (unsigned short*)(w + 25165824);   // 8,388,608
    unsigned short* WT   = (unsigned short*)(w + 33554432);   //   393,216
    unsigned short* w1K  = (unsigned short*)(w + 33947648);   //   393,216
    unsigned short* w2K  = (unsigned short*)(w + 34340864);   //   393,216
    unsigned short* attT = (unsigned short*)(w + 34734080);   // 8,404,992 (1026 rows/b)
    unsigned short* h1T  = (unsigned short*)(w + 43139072);   // 8,404,992
    float* colM = (float*)(w + 51544064);                     //    65,536
    float* colD = (float*)(w + 51609600);                     //    65,536
    float* rows = (float*)(w + 51675136);                     //    65,536
    float* wxp  = (float*)(w + 51740672);                     //    65,536
    unsigned short* S = (unsigned short*)(w + 51806208);      // nb * 2,097,152

    dim3 blk(256);

    txp_x<<<dim3(32, 8, 16), blk, 0, stream>>>(x, xT);
    txp_w<<<dim3(8, 8, 3), blk, 0, stream>>>(Wq, Wk, Wv, WT);
    wnorm_k<<<dim3(256), blk, 0, stream>>>(c1v, c1g, w1K);
    wnorm_k<<<dim3(256), blk, 0, stream>>>(c2v, c2g, w2K);
    zero_pads_k<<<dim3(32), blk, 0, stream>>>(attT, h1T);

    gemm_k<0><<<dim3(2, 8, 16), blk, 0, stream>>>(xT, WT,         qb, nullptr, bq, nullptr, nullptr, 0);
    gemm_k<0><<<dim3(2, 8, 16), blk, 0, stream>>>(xT, WT + 65536, kb, nullptr, bk, nullptr, nullptr, 0);
    gemm_k<1><<<dim3(8, 2, 16), blk, 0, stream>>>(WT + 131072, xT, vT, nullptr, bv, nullptr, nullptr, 0);

    // chunk the 2 MB/batch score buffer by available ws (deterministic in ws_size)
    size_t fixed = 51806208;
    size_t avail = (ws_size > fixed) ? ws_size - fixed : 0;
    int bmax = (int)(avail / 2097152);
    if (bmax < 1) bmax = 1;
    if (bmax > 16) bmax = 16;
    for (int b0 = 0; b0 < 16; b0 += bmax) {
        int nb = (16 - b0 < bmax) ? (16 - b0) : bmax;
        gemm_k<2><<<dim3(8, 8, nb), blk, 0, stream>>>(qb, kb, S, nullptr, nullptr, nullptr, nullptr, b0);
        colstats_k<<<dim3(16, nb), blk, 0, stream>>>(S, colM, colD, b0);
        pexp_k<<<dim3(1024, nb), blk, 0, stream>>>(S, colM, colD, rows, b0);
        gemm_k<3><<<dim3(2, 8, nb), blk, 0, stream>>>(S, vT, attT, nullptr, nullptr, nullptr, nullptr, b0);
    }
    wx_k<<<dim3(16), blk, 0, stream>>>(rows, wxp);
    gemm_k<4><<<dim3(2, 8, 16), blk, 0, stream>>>(attT, w1K, h1T, nullptr, c1b, nullptr, nullptr, 0);
    gemm_k<5><<<dim3(2, 8, 16), blk, 0, stream>>>(h1T, w2K, nullptr, out, c2b, x, wxp, 0);
}

// Round 4
// 262.509 us; speedup vs baseline: 6.5191x; 1.4170x over previous
//
#include <hip/hip_runtime.h>
#include <math.h>

typedef __attribute__((ext_vector_type(8))) short s16x8;
typedef __attribute__((ext_vector_type(4))) float f32x4;

__device__ __forceinline__ float b2f(unsigned short u) {
    unsigned int x = ((unsigned int)u) << 16;
    float f; __builtin_memcpy(&f, &x, 4); return f;
}
__device__ __forceinline__ unsigned short f2b(float f) {
    unsigned int x; __builtin_memcpy(&x, &f, 4);
    unsigned int r = x + 0x7FFFu + ((x >> 16) & 1u);
    return (unsigned short)(r >> 16);
}

__device__ __forceinline__ float blk_reduce_sum(float v, float* red) {
    int tid = threadIdx.x;
    red[tid] = v; __syncthreads();
    for (int off = 128; off > 0; off >>= 1) {
        if (tid < off) red[tid] += red[tid + off];
        __syncthreads();
    }
    float r = red[0]; __syncthreads();
    return r;
}

// ---------- prep: x [b][c][t] fp32 -> xT [b][t][c] bf16 ----------
__global__ __launch_bounds__(256) void txp_x(const float* __restrict__ x,
                                             unsigned short* __restrict__ xT) {
    __shared__ float t[32][33];
    int tt = blockIdx.x, ct = blockIdx.y, b = blockIdx.z;
    int col = threadIdx.x & 31, rq = threadIdx.x >> 5;
    const float* xb = x + (((size_t)b * 256 + ct * 32) << 10) + (tt << 5);
#pragma unroll
    for (int p = 0; p < 4; ++p) { int r = rq + p * 8; t[r][col] = xb[((size_t)r << 10) + col]; }
    __syncthreads();
    unsigned short* o = xT + ((size_t)b << 18) + ((size_t)(tt << 5) << 8) + (ct << 5);
#pragma unroll
    for (int p = 0; p < 4; ++p) { int tr = rq + p * 8; o[((size_t)tr << 8) + col] = f2b(t[col][tr]); }
}

// ---------- prep: Wq/Wk/Wv [c][k] fp32 -> WT [k][c] bf16 (3 matrices) ----------
__global__ __launch_bounds__(256) void txp_w(const float* __restrict__ Wq, const float* __restrict__ Wk,
                                             const float* __restrict__ Wv, unsigned short* __restrict__ WT) {
    __shared__ float t[32][33];
    int kt = blockIdx.x, ct = blockIdx.y, z = blockIdx.z;
    const float* W = (z == 0) ? Wq : (z == 1) ? Wk : Wv;
    int col = threadIdx.x & 31, rq = threadIdx.x >> 5;
    const float* wb = W + ((ct * 32) << 8) + (kt << 5);
#pragma unroll
    for (int p = 0; p < 4; ++p) { int r = rq + p * 8; t[r][col] = wb[(r << 8) + col]; }
    __syncthreads();
    unsigned short* o = WT + (z << 16) + ((kt << 5) << 8) + (ct << 5);
#pragma unroll
    for (int p = 0; p < 4; ++p) { int tr = rq + p * 8; o[(tr << 8) + col] = f2b(t[col][tr]); }
}

// ---------- prep: weight-norm conv weights -> wK [kk][o][ci] bf16 ----------
__global__ __launch_bounds__(256) void wnorm_k(const float* __restrict__ v, const float* __restrict__ g,
                                               unsigned short* __restrict__ wK) {
    __shared__ float red[256];
    int o = blockIdx.x, tid = threadIdx.x;
    float a0 = v[o * 768 + tid * 3 + 0];
    float a1 = v[o * 768 + tid * 3 + 1];
    float a2 = v[o * 768 + tid * 3 + 2];
    float tot = blk_reduce_sum(a0 * a0 + a1 * a1 + a2 * a2, red);
    float sc = g[o] / sqrtf(tot);
    wK[0 * 65536 + o * 256 + tid] = f2b(a0 * sc);
    wK[1 * 65536 + o * 256 + tid] = f2b(a1 * sc);
    wK[2 * 65536 + o * 256 + tid] = f2b(a2 * sc);
}

// ---------- zero the 2 leading pad rows of attT / h1T per batch ----------
__global__ void zero_pads_k(unsigned short* attT, unsigned short* h1T) {
    int idx = blockIdx.x * 256 + threadIdx.x;   // 32 blocks -> 8192 = 16b * 512
    int b = idx >> 9, r = idx & 511;
    attT[(size_t)b * 262656 + r] = 0;
    h1T[(size_t)b * 262656 + r] = 0;
}

// ---------- zero fp32 buffer ----------
__global__ void zero_f32_k(float* __restrict__ p, int n) {
    int i = blockIdx.x * 256 + threadIdx.x;
    if (i < n) p[i] = 0.f;
}

// ---------- generic bf16 MFMA GEMM: C = A . B^T  (A [M][K], B [N][K], K-contiguous) ----------
// 128x128 tile, 256 thr = 4 waves (2x2), each wave 64x64 = 4x4 frags of 16x16x32.
// MODE 0: q/k proj   out bf16 [t][256]+bias[col]
// MODE 1: v proj     out vT bf16 [c][1024]+bias[row]
// MODE 2: scores     out S bf16 [j][1024]*1/16, skip tiles nt>mt
// MODE 3: PV         A=P (chunk batch), B=vT, K=(mt+1)*128, out attT padded rows
// MODE 4: conv1      A=attT shifted 3 segs, B=w1K, +bias relu, out h1T padded
// MODE 5: conv2      A=h1T shifted, B=w2K, +bias relu, + x*(1+wx), relu, out fp32 [o][t]
template<int MODE>
__global__ __launch_bounds__(256) void gemm_k(const unsigned short* __restrict__ Ab,
                                              const unsigned short* __restrict__ Bb,
                                              unsigned short* __restrict__ o16,
                                              float* __restrict__ o32,
                                              const float* __restrict__ bias,
                                              const float* __restrict__ xres,
                                              const float* __restrict__ wxv, int b0) {
    int nt = blockIdx.x, mt = blockIdx.y, bz = blockIdx.z;
    if constexpr (MODE == 2) { if (nt > mt) return; }
    int b = b0 + bz;
    int m0 = mt << 7, n0 = nt << 7;
    constexpr int LDA = (MODE == 3) ? 1024 : 256;
    constexpr int LDB = (MODE == 3) ? 1024 : 256;
    const unsigned short* A;
    const unsigned short* B;
    if constexpr (MODE == 0)      { A = Ab + ((size_t)b << 18); B = Bb; }
    else if constexpr (MODE == 1) { A = Ab;                      B = Bb + ((size_t)b << 18); }
    else if constexpr (MODE == 2) { A = Ab + ((size_t)b << 18); B = Bb + ((size_t)b << 18); }
    else if constexpr (MODE == 3) { A = Ab + ((size_t)bz << 20); B = Bb + ((size_t)b << 18); }
    else                          { A = Ab + (size_t)b * 262656; B = Bb; }

    int tid = threadIdx.x;
    int wid = tid >> 6, lane = tid & 63;
    int wr = wid >> 1, wc = wid & 1;
    int lrow = lane & 15, koct = lane >> 4;
    int sr = tid >> 2, sk = (tid & 3) << 3;

    __shared__ short As[128 * 40];
    __shared__ short Bs[128 * 40];

    f32x4 acc[4][4];
#pragma unroll
    for (int m = 0; m < 4; ++m)
#pragma unroll
        for (int n = 0; n < 4; ++n) acc[m][n] = (f32x4){0.f, 0.f, 0.f, 0.f};

    constexpr int NSEG = (MODE >= 4) ? 3 : 1;
    int ksteps = (MODE == 3) ? ((mt + 1) << 2) : 8;

    for (int seg = 0; seg < NSEG; ++seg) {
        const unsigned short* Ar;
        const unsigned short* Br;
        if constexpr (MODE >= 4) {
            Ar = A + (size_t)(m0 + seg) * 256;            // shifted padded rows
            Br = B + (seg << 16) + (size_t)n0 * 256;      // weight plane kk=seg
        } else {
            Ar = A + (size_t)m0 * LDA;
            Br = B + (size_t)n0 * LDB;
        }
        for (int ks = 0; ks < ksteps; ++ks) {
            int k0 = ks << 5;
            __syncthreads();
            *(s16x8*)&As[sr * 40 + sk]        = *(const s16x8*)&Ar[(size_t)sr * LDA + k0 + sk];
            *(s16x8*)&As[(sr + 64) * 40 + sk] = *(const s16x8*)&Ar[(size_t)(sr + 64) * LDA + k0 + sk];
            *(s16x8*)&Bs[sr * 40 + sk]        = *(const s16x8*)&Br[(size_t)sr * LDB + k0 + sk];
            *(s16x8*)&Bs[(sr + 64) * 40 + sk] = *(const s16x8*)&Br[(size_t)(sr + 64) * LDB + k0 + sk];
            __syncthreads();
            s16x8 af[4], bf[4];
#pragma unroll
            for (int m = 0; m < 4; ++m)
                af[m] = *(const s16x8*)&As[(wr * 64 + m * 16 + lrow) * 40 + (koct << 3)];
#pragma unroll
            for (int n = 0; n < 4; ++n)
                bf[n] = *(const s16x8*)&Bs[(wc * 64 + n * 16 + lrow) * 40 + (koct << 3)];
#pragma unroll
            for (int m = 0; m < 4; ++m)
#pragma unroll
                for (int n = 0; n < 4; ++n)
                    acc[m][n] = __builtin_amdgcn_mfma_f32_16x16x32_bf16(af[m], bf[n], acc[m][n], 0, 0, 0);
        }
    }

    int rb = m0 + wr * 64 + koct * 4;
    int cb = n0 + wc * 64 + lrow;
#pragma unroll
    for (int m = 0; m < 4; ++m) {
#pragma unroll
        for (int n = 0; n < 4; ++n) {
            int col = cb + n * 16;
#pragma unroll
            for (int j = 0; j < 4; ++j) {
                int row = rb + m * 16 + j;
                float v = acc[m][n][j];
                if constexpr (MODE == 0) {
                    o16[((size_t)b << 18) + ((size_t)row << 8) + col] = f2b(v + bias[col]);
                } else if constexpr (MODE == 1) {
                    o16[((size_t)b << 18) + ((size_t)row << 10) + col] = f2b(v + bias[row]);
                } else if constexpr (MODE == 2) {
                    o16[((size_t)bz << 20) + ((size_t)row << 10) + col] = f2b(v * 0.0625f);
                } else if constexpr (MODE == 3) {
                    o16[(size_t)b * 262656 + ((size_t)(row + 2) << 8) + col] = f2b(v);
                } else if constexpr (MODE == 4) {
                    o16[(size_t)b * 262656 + ((size_t)(row + 2) << 8) + col] =
                        f2b(fmaxf(v + bias[col], 0.f));
                } else {
                    size_t oi = (((size_t)(b << 8) + col) << 10) + row;
                    float h = fmaxf(v + bias[col], 0.f);
                    h = fmaxf(h + xres[oi] * (1.f + wxv[(b << 10) + row]), 0.f);
                    o32[oi] = h;
                }
            }
        }
    }
}

// ---------- column sum-exp (softmax denominator over query axis j, M=0) ----------
// |S| <= ~10 for this problem's scales, so exp without max-subtraction is safe in fp32.
// grid (8 col-stripes, 8 j-slabs, nb); sub-diagonal slabs (jt<s) never written -> skip.
__global__ __launch_bounds__(256) void colsumexp_k(const unsigned short* __restrict__ S,
                                                   float* __restrict__ colD, int b0) {
    int s = blockIdx.x, jt = blockIdx.y, bz = blockIdx.z, b = b0 + bz;
    if (jt < s) return;
    int tid = threadIdx.x;
    int cg = tid & 31, rg = tid >> 5;        // 32 col-groups x 4 cols, 8 row-phases
    int i0 = (s << 7) + (cg << 2);
    const unsigned short* Sb = S + ((size_t)bz << 20) + ((size_t)(jt << 7) << 10);
    float a0 = 0.f, a1 = 0.f, a2 = 0.f, a3 = 0.f;
    if (jt == s) {
        for (int r = rg; r < 128; r += 8) {
            int j = (jt << 7) + r;
            ushort4 v = *(const ushort4*)&Sb[((size_t)r << 10) + i0];
            if (i0 + 0 <= j) a0 += expf(b2f(v.x));
            if (i0 + 1 <= j) a1 += expf(b2f(v.y));
            if (i0 + 2 <= j) a2 += expf(b2f(v.z));
            if (i0 + 3 <= j) a3 += expf(b2f(v.w));
        }
    } else {
        for (int r = rg; r < 128; r += 8) {
            ushort4 v = *(const ushort4*)&Sb[((size_t)r << 10) + i0];
            a0 += expf(b2f(v.x));
            a1 += expf(b2f(v.y));
            a2 += expf(b2f(v.z));
            a3 += expf(b2f(v.w));
        }
    }
    __shared__ float red[8][128];
    red[rg][(cg << 2) + 0] = a0;
    red[rg][(cg << 2) + 1] = a1;
    red[rg][(cg << 2) + 2] = a2;
    red[rg][(cg << 2) + 3] = a3;
    __syncthreads();
    if (tid < 128) {
        float t = 0.f;
#pragma unroll
        for (int g = 0; g < 8; ++g) t += red[g][tid];
        atomicAdd(&colD[(b << 10) + (s << 7) + tid], t);
    }
}

// ---------- P = exp(S)/colD (bf16 in place) + row sums ----------
__global__ __launch_bounds__(256) void pexp_k(unsigned short* __restrict__ S,
                                              const float* __restrict__ colD,
                                              float* __restrict__ rowsum, int b0) {
    int j = blockIdx.x, bz = blockIdx.y, b = b0 + bz;
    int tid = threadIdx.x;
    unsigned short* row = S + ((size_t)bz << 20) + ((size_t)j << 10);
    ushort4 s4 = *(const ushort4*)&row[tid << 2];
    float4 d4 = ((const float4*)(colD + (b << 10)))[tid];
    int i0 = tid << 2;
    float p0 = (i0 + 0 <= j) ? expf(b2f(s4.x)) / d4.x : 0.f;
    float p1 = (i0 + 1 <= j) ? expf(b2f(s4.y)) / d4.y : 0.f;
    float p2 = (i0 + 2 <= j) ? expf(b2f(s4.z)) / d4.z : 0.f;
    float p3 = (i0 + 3 <= j) ? expf(b2f(s4.w)) / d4.w : 0.f;
    ushort4 o;
    o.x = f2b(p0); o.y = f2b(p1); o.z = f2b(p2); o.w = f2b(p3);
    *(ushort4*)&row[tid << 2] = o;
    // rowsum: wave shuffle reduce, then merge 4 wave results via LDS
    float v = p0 + p1 + p2 + p3;
#pragma unroll
    for (int off = 32; off > 0; off >>= 1) v += __shfl_down(v, off, 64);
    __shared__ float sm[4];
    if ((tid & 63) == 0) sm[tid >> 6] = v;
    __syncthreads();
    if (tid == 0) rowsum[(b << 10) + j] = sm[0] + sm[1] + sm[2] + sm[3];
}

// ---------- weight_x[b][t] = softmax_t(rowsum) ----------
__global__ __launch_bounds__(256) void wx_k(const float* __restrict__ rowsum, float* __restrict__ wx) {
    int b = blockIdx.x, tid = threadIdx.x;
    __shared__ float red[256];
    float4 r4 = ((const float4*)(rowsum + ((size_t)b << 10)))[tid];
    float mx = fmaxf(fmaxf(r4.x, r4.y), fmaxf(r4.z, r4.w));
    red[tid] = mx; __syncthreads();
    for (int off = 128; off > 0; off >>= 1) {
        if (tid < off) red[tid] = fmaxf(red[tid], red[tid + off]);
        __syncthreads();
    }
    float M = red[0]; __syncthreads();
    float e0 = expf(r4.x - M), e1 = expf(r4.y - M), e2 = expf(r4.z - M), e3 = expf(r4.w - M);
    float Z = blk_reduce_sum(e0 + e1 + e2 + e3, red);
    float4 o = make_float4(e0 / Z, e1 / Z, e2 / Z, e3 / Z);
    ((float4*)(wx + ((size_t)b << 10)))[tid] = o;
}

extern "C" void kernel_launch(void* const* d_in, const int* in_sizes, int n_in,
                              void* d_out, int out_size, void* d_ws, size_t ws_size,
                              hipStream_t stream) {
    const float* x   = (const float*)d_in[0];
    const float* Wq  = (const float*)d_in[1];
    const float* bq  = (const float*)d_in[2];
    const float* Wk  = (const float*)d_in[3];
    const float* bk  = (const float*)d_in[4];
    const float* Wv  = (const float*)d_in[5];
    const float* bv  = (const float*)d_in[6];
    const float* c1v = (const float*)d_in[7];
    const float* c1g = (const float*)d_in[8];
    const float* c1b = (const float*)d_in[9];
    const float* c2v = (const float*)d_in[10];
    const float* c2g = (const float*)d_in[11];
    const float* c2b = (const float*)d_in[12];
    float* out = (float*)d_out;

    // ws layout in BYTES (all regions disjoint)
    char* w = (char*)d_ws;
    unsigned short* xT   = (unsigned short*)(w + 0);          // 8,388,608
    unsigned short* qb   = (unsigned short*)(w + 8388608);    // 8,388,608
    unsigned short* kb   = (unsigned short*)(w + 16777216);   // 8,388,608
    unsigned short* vT   = (unsigned short*)(w + 25165824);   // 8,388,608
    unsigned short* WT   = (unsigned short*)(w + 33554432);   //   393,216
    unsigned short* w1K  = (unsigned short*)(w + 33947648);   //   393,216
    unsigned short* w2K  = (unsigned short*)(w + 34340864);   //   393,216
    unsigned short* attT = (unsigned short*)(w + 34734080);   // 8,404,992 (1026 rows/b)
    unsigned short* h1T  = (unsigned short*)(w + 43139072);   // 8,404,992
    float* colD = (float*)(w + 51544064);                     //    65,536
    float* rows = (float*)(w + 51675136);                     //    65,536
    float* wxp  = (float*)(w + 51740672);                     //    65,536
    unsigned short* S = (unsigned short*)(w + 51806208);      // nb * 2,097,152

    dim3 blk(256);

    txp_x<<<dim3(32, 8, 16), blk, 0, stream>>>(x, xT);
    txp_w<<<dim3(8, 8, 3), blk, 0, stream>>>(Wq, Wk, Wv, WT);
    wnorm_k<<<dim3(256), blk, 0, stream>>>(c1v, c1g, w1K);
    wnorm_k<<<dim3(256), blk, 0, stream>>>(c2v, c2g, w2K);
    zero_pads_k<<<dim3(32), blk, 0, stream>>>(attT, h1T);
    zero_f32_k<<<dim3(64), blk, 0, stream>>>(colD, 16384);

    gemm_k<0><<<dim3(2, 8, 16), blk, 0, stream>>>(xT, WT,         qb, nullptr, bq, nullptr, nullptr, 0);
    gemm_k<0><<<dim3(2, 8, 16), blk, 0, stream>>>(xT, WT + 65536, kb, nullptr, bk, nullptr, nullptr, 0);
    gemm_k<1><<<dim3(8, 2, 16), blk, 0, stream>>>(WT + 131072, xT, vT, nullptr, bv, nullptr, nullptr, 0);

    // chunk the 2 MB/batch score buffer by available ws (deterministic in ws_size)
    size_t fixed = 51806208;
    size_t avail = (ws_size > fixed) ? ws_size - fixed : 0;
    int bmax = (int)(avail / 2097152);
    if (bmax < 1) bmax = 1;
    if (bmax > 16) bmax = 16;
    for (int b0 = 0; b0 < 16; b0 += bmax) {
        int nb = (16 - b0 < bmax) ? (16 - b0) : bmax;
        gemm_k<2><<<dim3(8, 8, nb), blk, 0, stream>>>(qb, kb, S, nullptr, nullptr, nullptr, nullptr, b0);
        colsumexp_k<<<dim3(8, 8, nb), blk, 0, stream>>>(S, colD, b0);
        pexp_k<<<dim3(1024, nb), blk, 0, stream>>>(S, colD, rows, b0);
        gemm_k<3><<<dim3(2, 8, nb), blk, 0, stream>>>(S, vT, attT, nullptr, nullptr, nullptr, nullptr, b0);
    }
    wx_k<<<dim3(16), blk, 0, stream>>>(rows, wxp);
    gemm_k<4><<<dim3(2, 8, 16), blk, 0, stream>>>(attT, w1K, h1T, nullptr, c1b, nullptr, nullptr, 0);
    gemm_k<5><<<dim3(2, 8, 16), blk, 0, stream>>>(h1T, w2K, nullptr, out, c2b, x, wxp, 0);
}

// Round 5
// 223.360 us; speedup vs baseline: 7.6618x; 1.1753x over previous
//
#include <hip/hip_runtime.h>
#include <math.h>

typedef __attribute__((ext_vector_type(8))) short s16x8;
typedef __attribute__((ext_vector_type(4))) float f32x4;

__device__ __forceinline__ float b2f(unsigned short u) {
    unsigned int x = ((unsigned int)u) << 16;
    float f; __builtin_memcpy(&f, &x, 4); return f;
}
__device__ __forceinline__ unsigned short f2b(float f) {
    unsigned int x; __builtin_memcpy(&x, &f, 4);
    unsigned int r = x + 0x7FFFu + ((x >> 16) & 1u);
    return (unsigned short)(r >> 16);
}

// async global->LDS, 16B per lane, linear LDS dest (guide §5 / m97)
#define GLDS(g, l) __builtin_amdgcn_global_load_lds( \
    (const __attribute__((address_space(1))) unsigned int*)(g), \
    (__attribute__((address_space(3))) unsigned int*)(l), 16, 0, 0)

__device__ __forceinline__ float blk_reduce_sum(float v, float* red) {
    int tid = threadIdx.x;
    red[tid] = v; __syncthreads();
    for (int off = 128; off > 0; off >>= 1) {
        if (tid < off) red[tid] += red[tid + off];
        __syncthreads();
    }
    float r = red[0]; __syncthreads();
    return r;
}

// ---------- prep: x [b][c][t] fp32 -> xT [b][t][c] bf16 ----------
__global__ __launch_bounds__(256) void txp_x(const float* __restrict__ x,
                                             unsigned short* __restrict__ xT) {
    __shared__ float t[32][33];
    int tt = blockIdx.x, ct = blockIdx.y, b = blockIdx.z;
    int col = threadIdx.x & 31, rq = threadIdx.x >> 5;
    const float* xb = x + (((size_t)b * 256 + ct * 32) << 10) + (tt << 5);
#pragma unroll
    for (int p = 0; p < 4; ++p) { int r = rq + p * 8; t[r][col] = xb[((size_t)r << 10) + col]; }
    __syncthreads();
    unsigned short* o = xT + ((size_t)b << 18) + ((size_t)(tt << 5) << 8) + (ct << 5);
#pragma unroll
    for (int p = 0; p < 4; ++p) { int tr = rq + p * 8; o[((size_t)tr << 8) + col] = f2b(t[col][tr]); }
}

// ---------- prep: Wq/Wk/Wv [c][k] fp32 -> WT [k][c] bf16 (3 matrices) ----------
__global__ __launch_bounds__(256) void txp_w(const float* __restrict__ Wq, const float* __restrict__ Wk,
                                             const float* __restrict__ Wv, unsigned short* __restrict__ WT) {
    __shared__ float t[32][33];
    int kt = blockIdx.x, ct = blockIdx.y, z = blockIdx.z;
    const float* W = (z == 0) ? Wq : (z == 1) ? Wk : Wv;
    int col = threadIdx.x & 31, rq = threadIdx.x >> 5;
    const float* wb = W + ((ct * 32) << 8) + (kt << 5);
#pragma unroll
    for (int p = 0; p < 4; ++p) { int r = rq + p * 8; t[r][col] = wb[(r << 8) + col]; }
    __syncthreads();
    unsigned short* o = WT + (z << 16) + ((kt << 5) << 8) + (ct << 5);
#pragma unroll
    for (int p = 0; p < 4; ++p) { int tr = rq + p * 8; o[(tr << 8) + col] = f2b(t[col][tr]); }
}

// ---------- prep: weight-norm both conv weights -> wK [kk][o][ci] bf16 (merged) ----------
__global__ __launch_bounds__(256) void wnorm_k(const float* __restrict__ v1, const float* __restrict__ g1,
                                               unsigned short* __restrict__ w1K,
                                               const float* __restrict__ v2, const float* __restrict__ g2,
                                               unsigned short* __restrict__ w2K) {
    __shared__ float red[256];
    int o = blockIdx.x & 255, tid = threadIdx.x;
    const float* v = (blockIdx.x >= 256) ? v2 : v1;
    const float* g = (blockIdx.x >= 256) ? g2 : g1;
    unsigned short* wK = (blockIdx.x >= 256) ? w2K : w1K;
    float a0 = v[o * 768 + tid * 3 + 0];
    float a1 = v[o * 768 + tid * 3 + 1];
    float a2 = v[o * 768 + tid * 3 + 2];
    float tot = blk_reduce_sum(a0 * a0 + a1 * a1 + a2 * a2, red);
    float sc = g[o] / sqrtf(tot);
    wK[0 * 65536 + o * 256 + tid] = f2b(a0 * sc);
    wK[1 * 65536 + o * 256 + tid] = f2b(a1 * sc);
    wK[2 * 65536 + o * 256 + tid] = f2b(a2 * sc);
}

// ---------- init: zero conv pad rows + colD ----------
__global__ void init_k(unsigned short* attT, unsigned short* h1T, float* colD) {
    int idx = blockIdx.x * 256 + threadIdx.x;   // grid 64 -> 16384
    colD[idx] = 0.f;
    if (idx < 8192) {
        int b = idx >> 9, r = idx & 511;
        attT[(size_t)b * 262656 + r] = 0;
        h1T[(size_t)b * 262656 + r] = 0;
    }
}

// ---------- generic bf16 MFMA GEMM: C = A . B^T  (A [M][K], B [N][K], K-contiguous) ----------
// 128x128 tile, 4 waves (2x2), gl_lds staging into linear [128][32] LDS tiles.
// MODE 0: q AND k proj (wy>=8 -> k), out bf16 [t][256]+bias[col]
// MODE 1: v proj     out vT bf16 [c][1024]+bias[row]
// MODE 2: scores     out E = exp(qk/16) bf16 [j][1024], masked->0, skip tiles nt>mt
// MODE 3: PV         A=E, B=vTs(=v/colD), K=(mt+1)*128, out attT padded rows;
//                    nt==0 blocks also fuse rowsum[j] = sum_i E[j][i]/colD[i] (bias=colD, o32=rows)
// MODE 4: conv1      A=attT shifted 3 segs, B=w1K, +bias relu, out h1T padded
// MODE 5: conv2      A=h1T shifted, B=w2K, +bias relu, + x*(1+wx), relu, out fp32 [o][t]
template<int MODE>
__global__ __launch_bounds__(256) void gemm_k(const unsigned short* __restrict__ Ab,
                                              const unsigned short* __restrict__ Bb,
                                              unsigned short* __restrict__ o16,
                                              float* __restrict__ o32,
                                              const float* __restrict__ bias,
                                              const float* __restrict__ xres,
                                              const float* __restrict__ wxv, int b0) {
    int nt = blockIdx.x, mt = blockIdx.y, bz = blockIdx.z;
    if constexpr (MODE == 2) { if (nt > mt) return; }
    bool isk = false;
    if constexpr (MODE == 0) { isk = (mt >= 8); mt &= 7; }
    int b = b0 + bz;
    int m0 = mt << 7, n0 = nt << 7;
    constexpr int LDA = (MODE == 3) ? 1024 : 256;
    constexpr int LDB = (MODE == 3) ? 1024 : 256;
    const unsigned short* A;
    const unsigned short* B;
    unsigned short* OB = o16;
    const float* BI = bias;
    if constexpr (MODE == 0)      { A = Ab + ((size_t)b << 18);
                                    B = isk ? Bb + 65536 : Bb;
                                    if (isk) { OB = (unsigned short*)o32; BI = xres; } }
    else if constexpr (MODE == 1) { A = Ab;                      B = Bb + ((size_t)b << 18); }
    else if constexpr (MODE == 2) { A = Ab + ((size_t)b << 18); B = Bb + ((size_t)b << 18); }
    else if constexpr (MODE == 3) { A = Ab + ((size_t)bz << 20); B = Bb + ((size_t)b << 18); }
    else                          { A = Ab + (size_t)b * 262656; B = Bb; }

    int tid = threadIdx.x;
    int wid = tid >> 6, lane = tid & 63;
    int wr = wid >> 1, wc = wid & 1;
    int lrow = lane & 15, koct = lane >> 4;
    int srow = tid >> 2, scol = (tid & 3) << 3;   // staging: row 0..63, col-group

    __shared__ short As[128 * 32];
    __shared__ short Bs[128 * 32];
    __shared__ float Rs[(MODE == 3) ? 1024 : 1];

    int ksteps = (MODE == 3) ? ((mt + 1) << 2) : 8;

    if constexpr (MODE == 3) {
        if (nt == 0)
            for (int i = tid; i < (ksteps << 5); i += 256)
                Rs[i] = 1.f / bias[(b << 10) + i];
    }
    float racc = 0.f;

    f32x4 acc[4][4];
#pragma unroll
    for (int m = 0; m < 4; ++m)
#pragma unroll
        for (int n = 0; n < 4; ++n) acc[m][n] = (f32x4){0.f, 0.f, 0.f, 0.f};

    constexpr int NSEG = (MODE >= 4) ? 3 : 1;

    for (int seg = 0; seg < NSEG; ++seg) {
        const unsigned short* Ar;
        const unsigned short* Br;
        if constexpr (MODE >= 4) {
            Ar = A + (size_t)(m0 + seg) * 256;            // shifted padded rows
            Br = B + (seg << 16) + (size_t)n0 * 256;      // weight plane kk=seg
        } else {
            Ar = A + (size_t)m0 * LDA;
            Br = B + (size_t)n0 * LDB;
        }
        for (int ks = 0; ks < ksteps; ++ks) {
            int k0 = ks << 5;
            __syncthreads();
            const unsigned short* ga = Ar + (size_t)srow * LDA + k0 + scol;
            const unsigned short* gb = Br + (size_t)srow * LDB + k0 + scol;
            GLDS(ga,                      &As[tid << 3]);
            GLDS(ga + (size_t)64 * LDA,   &As[(tid << 3) + 2048]);
            GLDS(gb,                      &Bs[tid << 3]);
            GLDS(gb + (size_t)64 * LDB,   &Bs[(tid << 3) + 2048]);
            __syncthreads();
            s16x8 af[4], bf[4];
#pragma unroll
            for (int m = 0; m < 4; ++m)
                af[m] = *(const s16x8*)&As[(wr * 64 + m * 16 + lrow) * 32 + (koct << 3)];
#pragma unroll
            for (int n = 0; n < 4; ++n)
                bf[n] = *(const s16x8*)&Bs[(wc * 64 + n * 16 + lrow) * 32 + (koct << 3)];
#pragma unroll
            for (int m = 0; m < 4; ++m)
#pragma unroll
                for (int n = 0; n < 4; ++n)
                    acc[m][n] = __builtin_amdgcn_mfma_f32_16x16x32_bf16(af[m], bf[n], acc[m][n], 0, 0, 0);
            if constexpr (MODE == 3) {
                if (nt == 0) {   // fused rowsum from the LDS-resident E tile
                    int rrow = tid >> 1, rh = (tid & 1) << 4;
                    s16x8 e0 = *(const s16x8*)&As[rrow * 32 + rh];
                    s16x8 e1 = *(const s16x8*)&As[rrow * 32 + rh + 8];
#pragma unroll
                    for (int c = 0; c < 8; ++c) racc += b2f((unsigned short)e0[c]) * Rs[k0 + rh + c];
#pragma unroll
                    for (int c = 0; c < 8; ++c) racc += b2f((unsigned short)e1[c]) * Rs[k0 + rh + 8 + c];
                }
            }
        }
    }

    if constexpr (MODE == 3) {
        if (nt == 0) {
            float other = __shfl_xor(racc, 1, 64);
            if ((tid & 1) == 0) o32[(b << 10) + (mt << 7) + (tid >> 1)] = racc + other;
        }
    }

    int rb = m0 + wr * 64 + koct * 4;
    int cb = n0 + wc * 64 + lrow;
#pragma unroll
    for (int m = 0; m < 4; ++m) {
#pragma unroll
        for (int n = 0; n < 4; ++n) {
            int col = cb + n * 16;
#pragma unroll
            for (int j = 0; j < 4; ++j) {
                int row = rb + m * 16 + j;
                float v = acc[m][n][j];
                if constexpr (MODE == 0) {
                    OB[((size_t)b << 18) + ((size_t)row << 8) + col] = f2b(v + BI[col]);
                } else if constexpr (MODE == 1) {
                    o16[((size_t)b << 18) + ((size_t)row << 10) + col] = f2b(v + BI[row]);
                } else if constexpr (MODE == 2) {
                    float e = (col <= row) ? expf(v * 0.0625f) : 0.f;
                    o16[((size_t)bz << 20) + ((size_t)row << 10) + col] = f2b(e);
                } else if constexpr (MODE == 3) {
                    o16[(size_t)b * 262656 + ((size_t)(row + 2) << 8) + col] = f2b(v);
                } else if constexpr (MODE == 4) {
                    o16[(size_t)b * 262656 + ((size_t)(row + 2) << 8) + col] =
                        f2b(fmaxf(v + BI[col], 0.f));
                } else {
                    size_t oi = (((size_t)(b << 8) + col) << 10) + row;
                    float h = fmaxf(v + BI[col], 0.f);
                    h = fmaxf(h + xres[oi] * (1.f + wxv[(b << 10) + row]), 0.f);
                    o32[oi] = h;
                }
            }
        }
    }
}

// ---------- column sums of E (softmax denominator over query axis j) ----------
// grid (8 col-stripes, 8 j-slabs, nb); slabs jt<s never written -> skip.
__global__ __launch_bounds__(256) void colsum_k(const unsigned short* __restrict__ S,
                                                float* __restrict__ colD, int b0) {
    int s = blockIdx.x, jt = blockIdx.y, bz = blockIdx.z, b = b0 + bz;
    if (jt < s) return;
    int tid = threadIdx.x;
    int cg = tid & 31, rg = tid >> 5;
    int i0 = (s << 7) + (cg << 2);
    const unsigned short* Sb = S + ((size_t)bz << 20) + ((size_t)(jt << 7) << 10);
    float a0 = 0.f, a1 = 0.f, a2 = 0.f, a3 = 0.f;
    for (int r = rg; r < 128; r += 8) {
        ushort4 v = *(const ushort4*)&Sb[((size_t)r << 10) + i0];
        a0 += b2f(v.x); a1 += b2f(v.y); a2 += b2f(v.z); a3 += b2f(v.w);
    }
    __shared__ float red[8][128];
    red[rg][(cg << 2) + 0] = a0;
    red[rg][(cg << 2) + 1] = a1;
    red[rg][(cg << 2) + 2] = a2;
    red[rg][(cg << 2) + 3] = a3;
    __syncthreads();
    if (tid < 128) {
        float t = 0.f;
#pragma unroll
        for (int g = 0; g < 8; ++g) t += red[g][tid];
        atomicAdd(&colD[(b << 10) + (s << 7) + tid], t);
    }
}

// ---------- vTs = vT / colD (in place, per key index i) ----------
__global__ __launch_bounds__(256) void vscale_k(unsigned short* __restrict__ vT,
                                                const float* __restrict__ colD, int b0) {
    int c = blockIdx.x, bz = blockIdx.y, b = b0 + bz;
    int tid = threadIdx.x;
    unsigned short* row = vT + ((size_t)b << 18) + ((size_t)c << 10);
    ushort4 v4 = *(const ushort4*)&row[tid << 2];
    float4 d4 = ((const float4*)(colD + (b << 10)))[tid];
    ushort4 o;
    o.x = f2b(b2f(v4.x) / d4.x);
    o.y = f2b(b2f(v4.y) / d4.y);
    o.z = f2b(b2f(v4.z) / d4.z);
    o.w = f2b(b2f(v4.w) / d4.w);
    *(ushort4*)&row[tid << 2] = o;
}

// ---------- weight_x[b][t] = softmax_t(rowsum) ----------
__global__ __launch_bounds__(256) void wx_k(const float* __restrict__ rowsum, float* __restrict__ wx) {
    int b = blockIdx.x, tid = threadIdx.x;
    __shared__ float red[256];
    float4 r4 = ((const float4*)(rowsum + ((size_t)b << 10)))[tid];
    float mx = fmaxf(fmaxf(r4.x, r4.y), fmaxf(r4.z, r4.w));
    red[tid] = mx; __syncthreads();
    for (int off = 128; off > 0; off >>= 1) {
        if (tid < off) red[tid] = fmaxf(red[tid], red[tid + off]);
        __syncthreads();
    }
    float M = red[0]; __syncthreads();
    float e0 = expf(r4.x - M), e1 = expf(r4.y - M), e2 = expf(r4.z - M), e3 = expf(r4.w - M);
    float Z = blk_reduce_sum(e0 + e1 + e2 + e3, red);
    float4 o = make_float4(e0 / Z, e1 / Z, e2 / Z, e3 / Z);
    ((float4*)(wx + ((size_t)b << 10)))[tid] = o;
}

extern "C" void kernel_launch(void* const* d_in, const int* in_sizes, int n_in,
                              void* d_out, int out_size, void* d_ws, size_t ws_size,
                              hipStream_t stream) {
    const float* x   = (const float*)d_in[0];
    const float* Wq  = (const float*)d_in[1];
    const float* bq  = (const float*)d_in[2];
    const float* Wk  = (const float*)d_in[3];
    const float* bk  = (const float*)d_in[4];
    const float* Wv  = (const float*)d_in[5];
    const float* bv  = (const float*)d_in[6];
    const float* c1v = (const float*)d_in[7];
    const float* c1g = (const float*)d_in[8];
    const float* c1b = (const float*)d_in[9];
    const float* c2v = (const float*)d_in[10];
    const float* c2g = (const float*)d_in[11];
    const float* c2b = (const float*)d_in[12];
    float* out = (float*)d_out;

    // ws layout in BYTES (all regions disjoint)
    char* w = (char*)d_ws;
    unsigned short* xT   = (unsigned short*)(w + 0);          // 8,388,608
    unsigned short* qb   = (unsigned short*)(w + 8388608);    // 8,388,608
    unsigned short* kb   = (unsigned short*)(w + 16777216);   // 8,388,608
    unsigned short* vT   = (unsigned short*)(w + 25165824);   // 8,388,608
    unsigned short* WT   = (unsigned short*)(w + 33554432);   //   393,216
    unsigned short* w1K  = (unsigned short*)(w + 33947648);   //   393,216
    unsigned short* w2K  = (unsigned short*)(w + 34340864);   //   393,216
    unsigned short* attT = (unsigned short*)(w + 34734080);   // 8,404,992 (1026 rows/b)
    unsigned short* h1T  = (unsigned short*)(w + 43139072);   // 8,404,992
    float* colD = (float*)(w + 51544064);                     //    65,536
    float* rows = (float*)(w + 51675136);                     //    65,536
    float* wxp  = (float*)(w + 51740672);                     //    65,536
    unsigned short* S = (unsigned short*)(w + 51806208);      // nb * 2,097,152

    dim3 blk(256);

    txp_x<<<dim3(32, 8, 16), blk, 0, stream>>>(x, xT);
    txp_w<<<dim3(8, 8, 3), blk, 0, stream>>>(Wq, Wk, Wv, WT);
    wnorm_k<<<dim3(512), blk, 0, stream>>>(c1v, c1g, w1K, c2v, c2g, w2K);
    init_k<<<dim3(64), blk, 0, stream>>>(attT, h1T, colD);

    // q and k in one launch (wy>=8 -> k); v projection
    gemm_k<0><<<dim3(2, 16, 16), blk, 0, stream>>>(xT, WT, qb, (float*)kb, bq, bk, nullptr, 0);
    gemm_k<1><<<dim3(8, 2, 16), blk, 0, stream>>>(WT + 131072, xT, vT, nullptr, bv, nullptr, nullptr, 0);

    // chunk the 2 MB/batch E buffer by available ws (deterministic in ws_size)
    size_t fixed = 51806208;
    size_t avail = (ws_size > fixed) ? ws_size - fixed : 0;
    int bmax = (int)(avail / 2097152);
    if (bmax < 1) bmax = 1;
    if (bmax > 16) bmax = 16;
    for (int b0 = 0; b0 < 16; b0 += bmax) {
        int nb = (16 - b0 < bmax) ? (16 - b0) : bmax;
        gemm_k<2><<<dim3(8, 8, nb), blk, 0, stream>>>(qb, kb, S, nullptr, nullptr, nullptr, nullptr, b0);
        colsum_k<<<dim3(8, 8, nb), blk, 0, stream>>>(S, colD, b0);
        vscale_k<<<dim3(256, nb), blk, 0, stream>>>(vT, colD, b0);
        gemm_k<3><<<dim3(2, 8, nb), blk, 0, stream>>>(S, vT, attT, rows, colD, nullptr, nullptr, b0);
    }
    wx_k<<<dim3(16), blk, 0, stream>>>(rows, wxp);
    gemm_k<4><<<dim3(2, 8, 16), blk, 0, stream>>>(attT, w1K, h1T, nullptr, c1b, nullptr, nullptr, 0);
    gemm_k<5><<<dim3(2, 8, 16), blk, 0, stream>>>(h1T, w2K, nullptr, out, c2b, x, wxp, 0);
}